// Round 2
// baseline (248.285 us; speedup 1.0000x reference)
//
#include <hip/hip_runtime.h>

typedef __attribute__((ext_vector_type(8))) __bf16 bf16x8;
typedef __attribute__((ext_vector_type(4))) __bf16 bf16x4;
typedef __attribute__((ext_vector_type(4))) float f32x4;

#define D_OUT 4096
#define D_IN  4096
#define RANK  512
#define MROWS 8192   // BATCH*SEQ = 4*2048

__device__ __forceinline__ void gload_lds16(const void* gsrc, void* ldst) {
  __builtin_amdgcn_global_load_lds(
      (const __attribute__((address_space(1))) void*)gsrc,
      (__attribute__((address_space(3))) void*)ldst, 16, 0, 0);
}

// ---------------- f32 -> bf16 elementwise convert (A only now) ----------------
__global__ __launch_bounds__(256) void cvt_f32_bf16(const float* __restrict__ in,
                                                    __bf16* __restrict__ out,
                                                    size_t n) {
  size_t i = ((size_t)blockIdx.x * 256 + threadIdx.x) * 4;
  size_t stride = (size_t)gridDim.x * 256 * 4;
  for (; i < n; i += stride) {
    float4 v = *(const float4*)(in + i);
    bf16x4 o = {(__bf16)v.x, (__bf16)v.y, (__bf16)v.z, (__bf16)v.w};
    *(bf16x4*)(out + i) = o;
  }
}

// ------------- f32 [R][C] -> bf16 [C][R] transpose-convert -------------
__global__ __launch_bounds__(256) void transpose_cvt(const float* __restrict__ in,
                                                     __bf16* __restrict__ out,
                                                     int R, int C) {
  __shared__ __bf16 tile[64][72];  // +8 pad
  const int r0 = blockIdx.x * 64, c0 = blockIdx.y * 64;
  const int t = threadIdx.x;
  const int tr = t / 16, tc4 = (t % 16) * 4;
#pragma unroll
  for (int i = 0; i < 4; ++i) {
    int r = i * 16 + tr;
    float4 v = *(const float4*)(in + (size_t)(r0 + r) * C + c0 + tc4);
    tile[r][tc4 + 0] = (__bf16)v.x;
    tile[r][tc4 + 1] = (__bf16)v.y;
    tile[r][tc4 + 2] = (__bf16)v.z;
    tile[r][tc4 + 3] = (__bf16)v.w;
  }
  __syncthreads();
#pragma unroll
  for (int i = 0; i < 4; ++i) {
    int c = i * 16 + tr;  // output row (n)
    bf16x4 o = {tile[tc4 + 0][c], tile[tc4 + 1][c], tile[tc4 + 2][c], tile[tc4 + 3][c]};
    *(bf16x4*)(out + (size_t)(c0 + c) * R + r0 + tc4) = o;
  }
}

// ---- GEMM1 fused: C[M,N] = cvt_bf16(Xf32[M,K]) @ Bmat[N,K]^T, bf16 out ----
// A-operand reg-staged from f32 with in-flight convert + swizzled ds_write.
// B-operand via global_load_lds (linear dest, inverse-swizzled source).
template <int BM, int BN, int BK>
__global__ __launch_bounds__(256) void gemm_xf32_bt(const float* __restrict__ Xf,
                                                    const __bf16* __restrict__ Bmat,
                                                    __bf16* __restrict__ Cout,
                                                    int M, int N, int K) {
  constexpr int WM = BM / 2, WN = BN / 2;
  constexpr int MI = WM / 16, NI = WN / 16;
  __shared__ alignas(16) __bf16 Al[BM * BK];
  __shared__ alignas(16) __bf16 Bl[BN * BK];

  const int tid = threadIdx.x;
  const int wid = tid >> 6;
  const int lane = tid & 63;
  const int l15 = lane & 15, lhi = lane >> 4;
  const int wr = wid >> 1, wc = wid & 1;

  // bijective XCD swizzle (nwg % 8 == 0 for our launches)
  const int nwg = gridDim.x * gridDim.y;
  const int bid = blockIdx.y * gridDim.x + blockIdx.x;
  const int swz = (bid & 7) * (nwg >> 3) + (bid >> 3);
  const int m0 = (swz % gridDim.x) * BM;
  const int n0 = (swz / gridDim.x) * BN;

  f32x4 acc[MI][NI] = {};

  constexpr int IA = BM * BK / (256 * 8);  // reg-staged f32 A iterations
  constexpr int IB = BN * BK / (256 * 8);  // gload_lds B iterations

  for (int k0 = 0; k0 < K; k0 += BK) {
    // ---- issue A f32 loads early (T14: issue-early / write-late) ----
    float4 av[IA][2];
#pragma unroll
    for (int it = 0; it < IA; ++it) {
      int o = (it * 256 + tid) * 8;
      int row = o / BK, col = o % BK;
      const float* src = Xf + (size_t)(m0 + row) * K + k0 + col;
      av[it][0] = *(const float4*)src;
      av[it][1] = *(const float4*)(src + 4);
    }
    // ---- B tile via global_load_lds, linear dest, inverse-swizzled src ----
#pragma unroll
    for (int it = 0; it < IB; ++it) {
      int o = (it * 256 + tid) * 8;
      int row = o / BK;
      int blk = (o % BK) / 8;
      int col = (blk ^ (row & 7)) * 8;
      gload_lds16(Bmat + (size_t)(n0 + row) * K + k0 + col,
                  Bl + (it * 256 + wid * 64) * 8);
    }
    // ---- convert + swizzled ds_write (same XOR as read side) ----
#pragma unroll
    for (int it = 0; it < IA; ++it) {
      int o = (it * 256 + tid) * 8;
      int row = o / BK;
      int blk = (o % BK) / 8;
      int swblk = blk ^ (row & 7);
      bf16x8 w = {(__bf16)av[it][0].x, (__bf16)av[it][0].y,
                  (__bf16)av[it][0].z, (__bf16)av[it][0].w,
                  (__bf16)av[it][1].x, (__bf16)av[it][1].y,
                  (__bf16)av[it][1].z, (__bf16)av[it][1].w};
      *(bf16x8*)((char*)Al + row * (BK * 2) + swblk * 16) = w;
    }
    __syncthreads();

#pragma unroll
    for (int kk = 0; kk < BK / 32; ++kk) {
      bf16x8 af[MI], bf[NI];
#pragma unroll
      for (int mi = 0; mi < MI; ++mi) {
        int row = wr * WM + mi * 16 + l15;
        int blk = (kk * 4 + lhi) ^ (row & 7);
        af[mi] = *(const bf16x8*)((const char*)Al + row * (BK * 2) + blk * 16);
      }
#pragma unroll
      for (int ni = 0; ni < NI; ++ni) {
        int row = wc * WN + ni * 16 + l15;
        int blk = (kk * 4 + lhi) ^ (row & 7);
        bf[ni] = *(const bf16x8*)((const char*)Bl + row * (BK * 2) + blk * 16);
      }
#pragma unroll
      for (int mi = 0; mi < MI; ++mi)
#pragma unroll
        for (int ni = 0; ni < NI; ++ni)
          acc[mi][ni] = __builtin_amdgcn_mfma_f32_16x16x32_bf16(af[mi], bf[ni],
                                                                acc[mi][ni], 0, 0, 0);
    }
    __syncthreads();
  }

#pragma unroll
  for (int ni = 0; ni < NI; ++ni) {
    int col = n0 + wc * WN + ni * 16 + l15;
#pragma unroll
    for (int mi = 0; mi < MI; ++mi) {
#pragma unroll
      for (int r = 0; r < 4; ++r) {
        int row = m0 + wr * WM + mi * 16 + lhi * 4 + r;
        Cout[(size_t)row * N + col] = (__bf16)acc[mi][ni][r];
      }
    }
  }
}

// ------------- GEMM2: C[M,N] = Amat[M,K] @ Bmat[N,K]^T + bias, f32 out -------------
template <int BM, int BN, int BK>
__global__ __launch_bounds__(256) void gemm_bt_bias(const __bf16* __restrict__ Amat,
                                                    const __bf16* __restrict__ Bmat,
                                                    const float* __restrict__ bias,
                                                    float* __restrict__ Cout,
                                                    int M, int N, int K) {
  constexpr int WM = BM / 2, WN = BN / 2;
  constexpr int MI = WM / 16, NI = WN / 16;
  __shared__ alignas(16) __bf16 Al[BM * BK];
  __shared__ alignas(16) __bf16 Bl[BN * BK];

  const int tid = threadIdx.x;
  const int wid = tid >> 6;
  const int lane = tid & 63;
  const int l15 = lane & 15, lhi = lane >> 4;
  const int wr = wid >> 1, wc = wid & 1;

  const int nwg = gridDim.x * gridDim.y;
  const int bid = blockIdx.y * gridDim.x + blockIdx.x;
  const int swz = (bid & 7) * (nwg >> 3) + (bid >> 3);
  const int m0 = (swz % gridDim.x) * BM;
  const int n0 = (swz / gridDim.x) * BN;

  f32x4 acc[MI][NI] = {};

  for (int k0 = 0; k0 < K; k0 += BK) {
    constexpr int IA = BM * BK / (256 * 8);
#pragma unroll
    for (int it = 0; it < IA; ++it) {
      int o = (it * 256 + tid) * 8;
      int row = o / BK;
      int blk = (o % BK) / 8;
      int col = (blk ^ (row & 7)) * 8;
      gload_lds16(Amat + (size_t)(m0 + row) * K + k0 + col,
                  Al + (it * 256 + wid * 64) * 8);
    }
    constexpr int IB = BN * BK / (256 * 8);
#pragma unroll
    for (int it = 0; it < IB; ++it) {
      int o = (it * 256 + tid) * 8;
      int row = o / BK;
      int blk = (o % BK) / 8;
      int col = (blk ^ (row & 7)) * 8;
      gload_lds16(Bmat + (size_t)(n0 + row) * K + k0 + col,
                  Bl + (it * 256 + wid * 64) * 8);
    }
    __syncthreads();

#pragma unroll
    for (int kk = 0; kk < BK / 32; ++kk) {
      bf16x8 af[MI], bf[NI];
#pragma unroll
      for (int mi = 0; mi < MI; ++mi) {
        int row = wr * WM + mi * 16 + l15;
        int blk = (kk * 4 + lhi) ^ (row & 7);
        af[mi] = *(const bf16x8*)((const char*)Al + row * (BK * 2) + blk * 16);
      }
#pragma unroll
      for (int ni = 0; ni < NI; ++ni) {
        int row = wc * WN + ni * 16 + l15;
        int blk = (kk * 4 + lhi) ^ (row & 7);
        bf[ni] = *(const bf16x8*)((const char*)Bl + row * (BK * 2) + blk * 16);
      }
#pragma unroll
      for (int mi = 0; mi < MI; ++mi)
#pragma unroll
        for (int ni = 0; ni < NI; ++ni)
          acc[mi][ni] = __builtin_amdgcn_mfma_f32_16x16x32_bf16(af[mi], bf[ni],
                                                                acc[mi][ni], 0, 0, 0);
    }
    __syncthreads();
  }

#pragma unroll
  for (int ni = 0; ni < NI; ++ni) {
    int col = n0 + wc * WN + ni * 16 + l15;
    float bv = bias[col];
#pragma unroll
    for (int mi = 0; mi < MI; ++mi) {
#pragma unroll
      for (int r = 0; r < 4; ++r) {
        int row = m0 + wr * WM + mi * 16 + lhi * 4 + r;
        Cout[(size_t)row * N + col] = acc[mi][ni][r] + bv;
      }
    }
  }
}

extern "C" void kernel_launch(void* const* d_in, const int* in_sizes, int n_in,
                              void* d_out, int out_size, void* d_ws, size_t ws_size,
                              hipStream_t stream) {
  const float* x    = (const float*)d_in[0];
  const float* A    = (const float*)d_in[1];
  const float* B    = (const float*)d_in[2];
  const float* bias = (const float*)d_in[3];
  float* out = (float*)d_out;

  char* ws = (char*)d_ws;
  __bf16* Ab = (__bf16*)ws;                        // [D_OUT][RANK] bf16, 4 MiB
  __bf16* Bt = (__bf16*)(ws + ((size_t)4 << 20));  // [RANK][D_IN]  bf16, 4 MiB
  __bf16* Tt = (__bf16*)(ws + ((size_t)8 << 20));  // [MROWS][RANK] bf16, 8 MiB

  hipLaunchKernelGGL(cvt_f32_bf16, dim3(512), dim3(256), 0, stream,
                     A, Ab, (size_t)D_OUT * RANK);
  hipLaunchKernelGGL(transpose_cvt, dim3(D_IN / 64, RANK / 64), dim3(256), 0, stream,
                     B, Bt, D_IN, RANK);
  // t = bf16(x) @ B   (fused cast; Bt is [RANK][D_IN] = [N,K])
  hipLaunchKernelGGL((gemm_xf32_bt<128, 64, 64>),
                     dim3(MROWS / 128, RANK / 64), dim3(256), 0, stream,
                     x, Bt, Tt, MROWS, RANK, D_IN);
  // out = t @ A^T + bias   (Ab is [D_OUT][RANK] = [N,K])
  hipLaunchKernelGGL((gemm_bt_bias<128, 128, 64>),
                     dim3(MROWS / 128, D_OUT / 128), dim3(256), 0, stream,
                     Tt, Ab, bias, out, MROWS, D_OUT, RANK);
}

// Round 3
// 173.673 us; speedup vs baseline: 1.4296x; 1.4296x over previous
//
#include <hip/hip_runtime.h>

typedef __attribute__((ext_vector_type(8))) __bf16 bf16x8;
typedef __attribute__((ext_vector_type(4))) __bf16 bf16x4;
typedef __attribute__((ext_vector_type(4))) float f32x4;

#define D_OUT 4096
#define D_IN  4096
#define RANK  512
#define MROWS 8192   // BATCH*SEQ

__device__ __forceinline__ void gload_lds16(const void* gsrc, void* ldst) {
  __builtin_amdgcn_global_load_lds(
      (const __attribute__((address_space(1))) void*)gsrc,
      (__attribute__((address_space(3))) void*)ldst, 16, 0, 0);
}

// ---------------- f32 -> bf16 elementwise convert ----------------
__global__ __launch_bounds__(256) void cvt_f32_bf16(const float* __restrict__ in,
                                                    __bf16* __restrict__ out,
                                                    size_t n) {
  size_t i = ((size_t)blockIdx.x * 256 + threadIdx.x) * 4;
  size_t stride = (size_t)gridDim.x * 256 * 4;
  for (; i < n; i += stride) {
    float4 v = *(const float4*)(in + i);
    bf16x4 o = {(__bf16)v.x, (__bf16)v.y, (__bf16)v.z, (__bf16)v.w};
    *(bf16x4*)(out + i) = o;
  }
}

// ------------- f32 [R][C] -> bf16 [C][R] transpose-convert -------------
__global__ __launch_bounds__(256) void transpose_cvt(const float* __restrict__ in,
                                                     __bf16* __restrict__ out,
                                                     int R, int C) {
  __shared__ __bf16 tile[64][72];
  const int r0 = blockIdx.x * 64, c0 = blockIdx.y * 64;
  const int t = threadIdx.x;
  const int tr = t / 16, tc4 = (t % 16) * 4;
#pragma unroll
  for (int i = 0; i < 4; ++i) {
    int r = i * 16 + tr;
    float4 v = *(const float4*)(in + (size_t)(r0 + r) * C + c0 + tc4);
    tile[r][tc4 + 0] = (__bf16)v.x;
    tile[r][tc4 + 1] = (__bf16)v.y;
    tile[r][tc4 + 2] = (__bf16)v.z;
    tile[r][tc4 + 3] = (__bf16)v.w;
  }
  __syncthreads();
#pragma unroll
  for (int i = 0; i < 4; ++i) {
    int c = i * 16 + tr;
    bf16x4 o = {tile[tc4 + 0][c], tile[tc4 + 1][c], tile[tc4 + 2][c], tile[tc4 + 3][c]};
    *(bf16x4*)(out + (size_t)(c0 + c) * R + r0 + tc4) = o;
  }
}

// ------------- GEMM1 (m97 structure): C[M,N] = A[M,K] @ B[N,K]^T, bf16 out -------------
template <int BM, int BN, int BK>
__global__ __launch_bounds__(256) void gemm_bt(const __bf16* __restrict__ Amat,
                                               const __bf16* __restrict__ Bmat,
                                               __bf16* __restrict__ Cout,
                                               int M, int N, int K) {
  constexpr int WM = BM / 2, WN = BN / 2;
  constexpr int MI = WM / 16, NI = WN / 16;
  __shared__ alignas(16) __bf16 Al[BM * BK];
  __shared__ alignas(16) __bf16 Bl[BN * BK];

  const int tid = threadIdx.x;
  const int wid = tid >> 6;
  const int lane = tid & 63;
  const int l15 = lane & 15, lhi = lane >> 4;
  const int wr = wid >> 1, wc = wid & 1;

  const int gx = gridDim.x;
  const int nwg = gx * gridDim.y;
  const int bid = blockIdx.y * gx + blockIdx.x;
  const int swz = (bid & 7) * (nwg >> 3) + (bid >> 3);
  const int m0 = (swz % gx) * BM;
  const int n0 = (swz / gx) * BN;

  f32x4 acc[MI][NI] = {};

  for (int k0 = 0; k0 < K; k0 += BK) {
    constexpr int IA = BM * BK / (256 * 8);
#pragma unroll
    for (int it = 0; it < IA; ++it) {
      int o = (it * 256 + tid) * 8;
      int row = o / BK;
      int blk = (o % BK) / 8;
      int col = (blk ^ (row & 7)) * 8;
      gload_lds16(Amat + (size_t)(m0 + row) * K + k0 + col,
                  Al + (it * 256 + wid * 64) * 8);
    }
    constexpr int IB = BN * BK / (256 * 8);
#pragma unroll
    for (int it = 0; it < IB; ++it) {
      int o = (it * 256 + tid) * 8;
      int row = o / BK;
      int blk = (o % BK) / 8;
      int col = (blk ^ (row & 7)) * 8;
      gload_lds16(Bmat + (size_t)(n0 + row) * K + k0 + col,
                  Bl + (it * 256 + wid * 64) * 8);
    }
    __syncthreads();

#pragma unroll
    for (int kk = 0; kk < BK / 32; ++kk) {
      bf16x8 af[MI], bfv[NI];
#pragma unroll
      for (int mi = 0; mi < MI; ++mi) {
        int row = wr * WM + mi * 16 + l15;
        int blk = (kk * 4 + lhi) ^ (row & 7);
        af[mi] = *(const bf16x8*)((const char*)Al + row * (BK * 2) + blk * 16);
      }
#pragma unroll
      for (int ni = 0; ni < NI; ++ni) {
        int row = wc * WN + ni * 16 + l15;
        int blk = (kk * 4 + lhi) ^ (row & 7);
        bfv[ni] = *(const bf16x8*)((const char*)Bl + row * (BK * 2) + blk * 16);
      }
#pragma unroll
      for (int mi = 0; mi < MI; ++mi)
#pragma unroll
        for (int ni = 0; ni < NI; ++ni)
          acc[mi][ni] = __builtin_amdgcn_mfma_f32_16x16x32_bf16(af[mi], bfv[ni],
                                                                acc[mi][ni], 0, 0, 0);
    }
    __syncthreads();
  }

#pragma unroll
  for (int ni = 0; ni < NI; ++ni) {
    int col = n0 + wc * WN + ni * 16 + l15;
#pragma unroll
    for (int mi = 0; mi < MI; ++mi) {
#pragma unroll
      for (int r = 0; r < 4; ++r) {
        int row = m0 + wr * WM + mi * 16 + lhi * 4 + r;
        Cout[(size_t)row * N + col] = (__bf16)acc[mi][ni][r];
      }
    }
  }
}

// ------------- GEMM2: 256x256 8-phase (T2+T3+T4+T5), f32 out + bias -------------
// 8 waves as 2M x 4N, per-wave 128x64. LDS 128 KiB (2 dbuf x (A 32K + B 32K)).
// Per K-tile (BK=64): 4 phases; each phase: ds_read subtile | stage 1 half-tile
// prefetch | barrier | lgkmcnt(0)+sched_barrier | setprio(1) 16 MFMA setprio(0)
// | barrier. Counted vmcnt(2) once per K-tile (drain only at the tail).
// Staging schedule (half h = 4t+j, one per phase): prologue h0..h4; phase p
// issues h = p+5. Buffer halves are only written after the end-of-phase-2
// barrier of the tile that reads them (all ds_reads happen in phases 0-2).
template <int NT>
__global__ __launch_bounds__(512, 1) void gemm2_8ph(const __bf16* __restrict__ Amat,
                                                    const __bf16* __restrict__ Bmat,
                                                    const float* __restrict__ bias,
                                                    float* __restrict__ Cout,
                                                    int M, int N, int K) {
  __shared__ alignas(16) __bf16 sm[2 * 32768];  // [buf][A 16384 | B 16384] elems

  const int tid = threadIdx.x;
  const int wid = tid >> 6;
  const int lane = tid & 63;
  const int l15 = lane & 15, lhi = lane >> 4;
  const int wr = wid >> 2, wc = wid & 3;  // 2M x 4N

  const int gx = gridDim.x;
  const int nwg = gx * gridDim.y;
  const int bid = blockIdx.y * gx + blockIdx.x;
  const int swz = (bid & 7) * (nwg >> 3) + (bid >> 3);
  const int m0 = (swz % gx) * 256;
  const int n0 = (swz / gx) * 256;

  f32x4 acc[8][4] = {};
  bf16x8 af[4][2];       // current mh half of A fragments
  bf16x8 bfr[2][2][2];   // both nh halves of B fragments

#define STAGE(tt, jj) do {                                                        \
    const __bf16* _src = ((jj) < 2)                                               \
        ? Amat + (size_t)(m0 + (jj) * 128) * K + (tt) * 64                        \
        : Bmat + (size_t)(n0 + ((jj)-2) * 128) * K + (tt) * 64;                   \
    __bf16* _dst = sm + ((tt) & 1) * 32768 +                                      \
                   (((jj) < 2) ? (jj) * 8192 : 16384 + ((jj)-2) * 8192);          \
    _Pragma("unroll")                                                             \
    for (int _it = 0; _it < 2; ++_it) {                                           \
      int _o = (_it * 512 + tid) * 8;                                             \
      int _row = _o >> 6;                                                         \
      int _blk = (_o & 63) >> 3;                                                  \
      int _col = (_blk ^ (_row & 7)) * 8;                                         \
      gload_lds16(_src + (size_t)_row * K + _col,                                 \
                  _dst + (_it * 512 + wid * 64) * 8);                             \
    }                                                                             \
  } while (0)

#define LDA8(tt, mh) do {                                                         \
    const char* _b = (const char*)(sm + ((tt) & 1) * 32768);                      \
    _Pragma("unroll")                                                             \
    for (int _mi = 0; _mi < 4; ++_mi)                                             \
      _Pragma("unroll")                                                           \
      for (int _kk = 0; _kk < 2; ++_kk) {                                         \
        int _r = wr * 128 + (mh) * 64 + _mi * 16 + l15;                           \
        int _blk = (_kk * 4 + lhi) ^ (_r & 7);                                    \
        af[_mi][_kk] = *(const bf16x8*)(_b + _r * 128 + _blk * 16);               \
      }                                                                           \
  } while (0)

#define LDB4(tt, nh) do {                                                         \
    const char* _b = (const char*)(sm + ((tt) & 1) * 32768 + 16384);              \
    _Pragma("unroll")                                                             \
    for (int _ni = 0; _ni < 2; ++_ni)                                             \
      _Pragma("unroll")                                                           \
      for (int _kk = 0; _kk < 2; ++_kk) {                                         \
        int _r = wc * 64 + (nh) * 32 + _ni * 16 + l15;                            \
        int _blk = (_kk * 4 + lhi) ^ (_r & 7);                                    \
        bfr[nh][_ni][_kk] = *(const bf16x8*)(_b + _r * 128 + _blk * 16);          \
      }                                                                           \
  } while (0)

#define MMA16(mh, nh) do {                                                        \
    _Pragma("unroll")                                                             \
    for (int _mi = 0; _mi < 4; ++_mi)                                             \
      _Pragma("unroll")                                                           \
      for (int _ni = 0; _ni < 2; ++_ni)                                           \
        _Pragma("unroll")                                                         \
        for (int _kk = 0; _kk < 2; ++_kk)                                         \
          acc[(mh) * 4 + _mi][(nh) * 2 + _ni] =                                   \
              __builtin_amdgcn_mfma_f32_16x16x32_bf16(                            \
                  af[_mi][_kk], bfr[nh][_ni][_kk],                                \
                  acc[(mh) * 4 + _mi][(nh) * 2 + _ni], 0, 0, 0);                  \
  } while (0)

  // ---- prologue: tile 0 fully + tile 1 half 0 ----
  STAGE(0, 0); STAGE(0, 1); STAGE(0, 2); STAGE(0, 3);
  STAGE(1, 0);
  asm volatile("s_waitcnt vmcnt(2)" ::: "memory");
  __builtin_amdgcn_s_barrier();

  for (int t = 0; t < NT; ++t) {
    // ---- phase 0: A[mh0] (8 reads) + B[nh0] (4 reads); stage (t+1, A1) ----
    LDA8(t, 0); LDB4(t, 0);
    if (t + 1 < NT) STAGE(t + 1, 1);
    __builtin_amdgcn_s_barrier();
    asm volatile("s_waitcnt lgkmcnt(0)" ::: "memory");
    __builtin_amdgcn_sched_barrier(0);
    __builtin_amdgcn_s_setprio(1);
    MMA16(0, 0);
    __builtin_amdgcn_s_setprio(0);
    __builtin_amdgcn_s_barrier();

    // ---- phase 1: B[nh1] (4 reads); stage (t+1, B0) ----
    LDB4(t, 1);
    if (t + 1 < NT) STAGE(t + 1, 2);
    __builtin_amdgcn_s_barrier();
    asm volatile("s_waitcnt lgkmcnt(0)" ::: "memory");
    __builtin_amdgcn_sched_barrier(0);
    __builtin_amdgcn_s_setprio(1);
    MMA16(0, 1);
    __builtin_amdgcn_s_setprio(0);
    __builtin_amdgcn_s_barrier();

    // ---- phase 2: A[mh1] (8 reads); stage (t+1, B1) ----
    LDA8(t, 1);
    if (t + 1 < NT) STAGE(t + 1, 3);
    __builtin_amdgcn_s_barrier();
    asm volatile("s_waitcnt lgkmcnt(0)" ::: "memory");
    __builtin_amdgcn_sched_barrier(0);
    __builtin_amdgcn_s_setprio(1);
    MMA16(1, 1);
    __builtin_amdgcn_s_setprio(0);
    __builtin_amdgcn_s_barrier();   // <- after this, buf[t&1] is fully read-out

    // ---- phase 3: no reads; stage (t+2, A0) into own (now-free) buffer ----
    if (t + 2 < NT) STAGE(t + 2, 0);
    __builtin_amdgcn_s_barrier();
    __builtin_amdgcn_s_setprio(1);
    MMA16(1, 0);
    __builtin_amdgcn_s_setprio(0);
    if (t < NT - 2) {
      asm volatile("s_waitcnt vmcnt(2)" ::: "memory");  // tile t+1 landed
    } else if (t == NT - 2) {
      asm volatile("s_waitcnt vmcnt(0)" ::: "memory");  // tail drain
    }
    __builtin_amdgcn_s_barrier();
  }

#undef STAGE
#undef LDA8
#undef LDB4
#undef MMA16

  // ---- epilogue: C/D layout col=lane&15, row=(lane>>4)*4+reg ----
#pragma unroll
  for (int ni = 0; ni < 4; ++ni) {
    int col = n0 + wc * 64 + ni * 16 + l15;
    float bv = bias[col];
#pragma unroll
    for (int mi = 0; mi < 8; ++mi) {
#pragma unroll
      for (int r = 0; r < 4; ++r) {
        int row = m0 + wr * 128 + mi * 16 + lhi * 4 + r;
        Cout[(size_t)row * N + col] = acc[mi][ni][r] + bv;
      }
    }
  }
}

extern "C" void kernel_launch(void* const* d_in, const int* in_sizes, int n_in,
                              void* d_out, int out_size, void* d_ws, size_t ws_size,
                              hipStream_t stream) {
  const float* x    = (const float*)d_in[0];
  const float* A    = (const float*)d_in[1];
  const float* B    = (const float*)d_in[2];
  const float* bias = (const float*)d_in[3];
  float* out = (float*)d_out;

  // x_bf16 in the front 64 MiB of d_out (consumed by GEMM1 before GEMM2 writes).
  __bf16* xb = (__bf16*)d_out;
  char* ws = (char*)d_ws;
  __bf16* Ab = (__bf16*)ws;                        // [D_OUT][RANK] bf16
  __bf16* Bt = (__bf16*)(ws + ((size_t)4 << 20));  // [RANK][D_IN]  bf16
  __bf16* Tt = (__bf16*)(ws + ((size_t)8 << 20));  // [MROWS][RANK] bf16

  hipLaunchKernelGGL(cvt_f32_bf16, dim3(2048), dim3(256), 0, stream,
                     x, xb, (size_t)MROWS * D_IN);
  hipLaunchKernelGGL(cvt_f32_bf16, dim3(512), dim3(256), 0, stream,
                     A, Ab, (size_t)D_OUT * RANK);
  hipLaunchKernelGGL(transpose_cvt, dim3(D_IN / 64, RANK / 64), dim3(256), 0, stream,
                     B, Bt, D_IN, RANK);
  // t = bf16(x) @ B
  hipLaunchKernelGGL((gemm_bt<128, 64, 64>),
                     dim3(MROWS / 128, RANK / 64), dim3(256), 0, stream,
                     xb, Bt, Tt, MROWS, RANK, D_IN);
  // out = t @ A^T + bias  (K = 512 -> NT = 8 K-tiles)
  hipLaunchKernelGGL((gemm2_8ph<8>),
                     dim3(MROWS / 256, D_OUT / 256), dim3(512), 0, stream,
                     Tt, Ab, bias, out, MROWS, D_OUT, RANK);
}

// Round 4
// 167.026 us; speedup vs baseline: 1.4865x; 1.0398x over previous
//
#include <hip/hip_runtime.h>

typedef __attribute__((ext_vector_type(8))) __bf16 bf16x8;
typedef __attribute__((ext_vector_type(4))) __bf16 bf16x4;
typedef __attribute__((ext_vector_type(4))) float f32x4;

#define D_OUT 4096
#define D_IN  4096
#define RANK  512
#define MROWS 8192   // BATCH*SEQ

__device__ __forceinline__ void gload_lds16(const void* gsrc, void* ldst) {
  __builtin_amdgcn_global_load_lds(
      (const __attribute__((address_space(1))) void*)gsrc,
      (__attribute__((address_space(3))) void*)ldst, 16, 0, 0);
}

// ---------------- f32 -> bf16 elementwise convert ----------------
__global__ __launch_bounds__(256) void cvt_f32_bf16(const float* __restrict__ in,
                                                    __bf16* __restrict__ out,
                                                    size_t n) {
  size_t i = ((size_t)blockIdx.x * 256 + threadIdx.x) * 4;
  size_t stride = (size_t)gridDim.x * 256 * 4;
  for (; i < n; i += stride) {
    float4 v = *(const float4*)(in + i);
    bf16x4 o = {(__bf16)v.x, (__bf16)v.y, (__bf16)v.z, (__bf16)v.w};
    *(bf16x4*)(out + i) = o;
  }
}

// ------------- f32 [R][C] -> bf16 [C][R] transpose-convert -------------
__global__ __launch_bounds__(256) void transpose_cvt(const float* __restrict__ in,
                                                     __bf16* __restrict__ out,
                                                     int R, int C) {
  __shared__ __bf16 tile[64][72];
  const int r0 = blockIdx.x * 64, c0 = blockIdx.y * 64;
  const int t = threadIdx.x;
  const int tr = t / 16, tc4 = (t % 16) * 4;
#pragma unroll
  for (int i = 0; i < 4; ++i) {
    int r = i * 16 + tr;
    float4 v = *(const float4*)(in + (size_t)(r0 + r) * C + c0 + tc4);
    tile[r][tc4 + 0] = (__bf16)v.x;
    tile[r][tc4 + 1] = (__bf16)v.y;
    tile[r][tc4 + 2] = (__bf16)v.z;
    tile[r][tc4 + 3] = (__bf16)v.w;
  }
  __syncthreads();
#pragma unroll
  for (int i = 0; i < 4; ++i) {
    int c = i * 16 + tr;
    bf16x4 o = {tile[tc4 + 0][c], tile[tc4 + 1][c], tile[tc4 + 2][c], tile[tc4 + 3][c]};
    *(bf16x4*)(out + (size_t)(c0 + c) * R + r0 + tc4) = o;
  }
}

// ---------------- partial-sum reduce + cvt: o = bf16(t0 + t1) ----------------
__global__ __launch_bounds__(256) void reduce2_bf16(const __bf16* __restrict__ t0,
                                                    const __bf16* __restrict__ t1,
                                                    __bf16* __restrict__ o) {
  size_t i = ((size_t)blockIdx.x * 256 + threadIdx.x) * 8;
  bf16x8 a = *(const bf16x8*)(t0 + i);
  bf16x8 b = *(const bf16x8*)(t1 + i);
  bf16x8 r;
#pragma unroll
  for (int j = 0; j < 8; ++j) r[j] = (__bf16)((float)a[j] + (float)b[j]);
  *(bf16x8*)(o + i) = r;
}

// ------------- GEMM (m97 structure): C[M,N] = A[M,:] @ B[N,:]^T (+bias) -------------
// K-split via blockIdx.z: each z computes Kred columns starting at z*Kred
// (row stride ldk), writing to its own C slice (Cout + z*M*N).
// global_load_lds width-16 staging, XOR-swizzled LDS, 4 waves as 2x2.
template <int BM, int BN, int BK, bool OUT_F32, bool BIAS>
__global__ __launch_bounds__(256) void gemm_bt(const __bf16* __restrict__ Amat,
                                               const __bf16* __restrict__ Bmat,
                                               const float* __restrict__ bias,
                                               void* __restrict__ Cout,
                                               int M, int N, int Kred, int ldk) {
  constexpr int WM = BM / 2, WN = BN / 2;
  constexpr int MI = WM / 16, NI = WN / 16;
  __shared__ alignas(16) __bf16 Al[BM * BK];
  __shared__ alignas(16) __bf16 Bl[BN * BK];

  const int tid = threadIdx.x;
  const int wid = tid >> 6;
  const int lane = tid & 63;
  const int l15 = lane & 15, lhi = lane >> 4;
  const int wr = wid >> 1, wc = wid & 1;

  // bijective XCD swizzle over the x-y plane (nwg % 8 == 0 for our launches)
  const int gx = gridDim.x;
  const int nwg = gx * gridDim.y;
  const int bid = blockIdx.y * gx + blockIdx.x;
  const int swz = (bid & 7) * (nwg >> 3) + (bid >> 3);
  const int m0 = (swz % gx) * BM;
  const int n0 = (swz / gx) * BN;
  const int kbase = blockIdx.z * Kred;

  f32x4 acc[MI][NI] = {};

  for (int k0 = kbase; k0 < kbase + Kred; k0 += BK) {
    constexpr int IA = BM * BK / (256 * 8);
#pragma unroll
    for (int it = 0; it < IA; ++it) {
      int o = (it * 256 + tid) * 8;
      int row = o / BK;
      int blk = (o % BK) / 8;
      int col = (blk ^ (row & 7)) * 8;
      gload_lds16(Amat + (size_t)(m0 + row) * ldk + k0 + col,
                  Al + (it * 256 + wid * 64) * 8);
    }
    constexpr int IB = BN * BK / (256 * 8);
#pragma unroll
    for (int it = 0; it < IB; ++it) {
      int o = (it * 256 + tid) * 8;
      int row = o / BK;
      int blk = (o % BK) / 8;
      int col = (blk ^ (row & 7)) * 8;
      gload_lds16(Bmat + (size_t)(n0 + row) * ldk + k0 + col,
                  Bl + (it * 256 + wid * 64) * 8);
    }
    __syncthreads();

#pragma unroll
    for (int kk = 0; kk < BK / 32; ++kk) {
      bf16x8 af[MI], bfv[NI];
#pragma unroll
      for (int mi = 0; mi < MI; ++mi) {
        int row = wr * WM + mi * 16 + l15;
        int blk = (kk * 4 + lhi) ^ (row & 7);
        af[mi] = *(const bf16x8*)((const char*)Al + row * (BK * 2) + blk * 16);
      }
#pragma unroll
      for (int ni = 0; ni < NI; ++ni) {
        int row = wc * WN + ni * 16 + l15;
        int blk = (kk * 4 + lhi) ^ (row & 7);
        bfv[ni] = *(const bf16x8*)((const char*)Bl + row * (BK * 2) + blk * 16);
      }
#pragma unroll
      for (int mi = 0; mi < MI; ++mi)
#pragma unroll
        for (int ni = 0; ni < NI; ++ni)
          acc[mi][ni] = __builtin_amdgcn_mfma_f32_16x16x32_bf16(af[mi], bfv[ni],
                                                                acc[mi][ni], 0, 0, 0);
    }
    __syncthreads();
  }

  // ---- epilogue: C/D layout col=lane&15, row=(lane>>4)*4+reg ----
  char* cbase = (char*)Cout + (size_t)blockIdx.z * M * N * (OUT_F32 ? 4 : 2);
#pragma unroll
  for (int ni = 0; ni < NI; ++ni) {
    int col = n0 + wc * WN + ni * 16 + l15;
    float bv = 0.f;
    if constexpr (BIAS) bv = bias[col];
#pragma unroll
    for (int mi = 0; mi < MI; ++mi) {
#pragma unroll
      for (int r = 0; r < 4; ++r) {
        int row = m0 + wr * WM + mi * 16 + lhi * 4 + r;
        if constexpr (OUT_F32)
          ((float*)cbase)[(size_t)row * N + col] = acc[mi][ni][r] + bv;
        else
          ((__bf16*)cbase)[(size_t)row * N + col] = (__bf16)acc[mi][ni][r];
      }
    }
  }
}

extern "C" void kernel_launch(void* const* d_in, const int* in_sizes, int n_in,
                              void* d_out, int out_size, void* d_ws, size_t ws_size,
                              hipStream_t stream) {
  const float* x    = (const float*)d_in[0];
  const float* A    = (const float*)d_in[1];
  const float* B    = (const float*)d_in[2];
  const float* bias = (const float*)d_in[3];
  float* out = (float*)d_out;

  // d_out (128+ MiB) doubles as scratch before GEMM2 overwrites it:
  //   [0, 64 MiB)  : xb  = bf16(x)            (consumed by GEMM1)
  //   [64, 80 MiB) : tp  = split-K partials   (consumed by reduce2)
  __bf16* xb = (__bf16*)d_out;
  __bf16* tp = (__bf16*)((char*)d_out + ((size_t)64 << 20));
  char* ws = (char*)d_ws;
  __bf16* Ab = (__bf16*)ws;                        // [D_OUT][RANK] bf16
  __bf16* Bt = (__bf16*)(ws + ((size_t)4 << 20));  // [RANK][D_IN]  bf16
  __bf16* Tt = (__bf16*)(ws + ((size_t)8 << 20));  // [MROWS][RANK] bf16

  hipLaunchKernelGGL(cvt_f32_bf16, dim3(2048), dim3(256), 0, stream,
                     x, xb, (size_t)MROWS * D_IN);
  hipLaunchKernelGGL(cvt_f32_bf16, dim3(512), dim3(256), 0, stream,
                     A, Ab, (size_t)D_OUT * RANK);
  hipLaunchKernelGGL(transpose_cvt, dim3(D_IN / 64, RANK / 64), dim3(256), 0, stream,
                     B, Bt, D_IN, RANK);
  // t_partial[z] = bf16(x) @ B[:, z*2048:(z+1)*2048]   (split-K=2, 128x128 tiles)
  hipLaunchKernelGGL((gemm_bt<128, 128, 64, false, false>),
                     dim3(MROWS / 128, RANK / 128, 2), dim3(256), 0, stream,
                     xb, Bt, nullptr, tp, MROWS, RANK, D_IN / 2, D_IN);
  // Tt = bf16(tp[0] + tp[1])
  hipLaunchKernelGGL(reduce2_bf16, dim3(MROWS * RANK / (256 * 8)), dim3(256), 0, stream,
                     tp, tp + (size_t)MROWS * RANK, Tt);
  // out = Tt @ A^T + bias
  hipLaunchKernelGGL((gemm_bt<128, 128, 64, true, true>),
                     dim3(MROWS / 128, D_OUT / 128, 1), dim3(256), 0, stream,
                     Tt, Ab, bias, out, MROWS, D_OUT, RANK, RANK);
}

// Round 5
// 162.331 us; speedup vs baseline: 1.5295x; 1.0289x over previous
//
#include <hip/hip_runtime.h>

typedef __attribute__((ext_vector_type(8))) __bf16 bf16x8;
typedef __attribute__((ext_vector_type(4))) __bf16 bf16x4;
typedef __attribute__((ext_vector_type(4))) float f32x4;

#define D_OUT 4096
#define D_IN  4096
#define RANK  512
#define MROWS 8192   // BATCH*SEQ

__device__ __forceinline__ void gload_lds16(const void* gsrc, void* ldst) {
  __builtin_amdgcn_global_load_lds(
      (const __attribute__((address_space(1))) void*)gsrc,
      (__attribute__((address_space(3))) void*)ldst, 16, 0, 0);
}

// ---------------- f32 -> bf16 elementwise convert ----------------
__global__ __launch_bounds__(256) void cvt_f32_bf16(const float* __restrict__ in,
                                                    __bf16* __restrict__ out,
                                                    size_t n) {
  size_t i = ((size_t)blockIdx.x * 256 + threadIdx.x) * 4;
  size_t stride = (size_t)gridDim.x * 256 * 4;
  for (; i < n; i += stride) {
    float4 v = *(const float4*)(in + i);
    bf16x4 o = {(__bf16)v.x, (__bf16)v.y, (__bf16)v.z, (__bf16)v.w};
    *(bf16x4*)(out + i) = o;
  }
}

// ------------- f32 [R][C] -> bf16 [C][R] transpose-convert -------------
__global__ __launch_bounds__(256) void transpose_cvt(const float* __restrict__ in,
                                                     __bf16* __restrict__ out,
                                                     int R, int C) {
  __shared__ __bf16 tile[64][72];
  const int r0 = blockIdx.x * 64, c0 = blockIdx.y * 64;
  const int t = threadIdx.x;
  const int tr = t / 16, tc4 = (t % 16) * 4;
#pragma unroll
  for (int i = 0; i < 4; ++i) {
    int r = i * 16 + tr;
    float4 v = *(const float4*)(in + (size_t)(r0 + r) * C + c0 + tc4);
    tile[r][tc4 + 0] = (__bf16)v.x;
    tile[r][tc4 + 1] = (__bf16)v.y;
    tile[r][tc4 + 2] = (__bf16)v.z;
    tile[r][tc4 + 3] = (__bf16)v.w;
  }
  __syncthreads();
#pragma unroll
  for (int i = 0; i < 4; ++i) {
    int c = i * 16 + tr;
    bf16x4 o = {tile[tc4 + 0][c], tile[tc4 + 1][c], tile[tc4 + 2][c], tile[tc4 + 3][c]};
    *(bf16x4*)(out + (size_t)(c0 + c) * R + r0 + tc4) = o;
  }
}

// ---------------- partial-sum reduce + cvt: o = bf16(t0 + t1) ----------------
__global__ __launch_bounds__(256) void reduce2_bf16(const __bf16* __restrict__ t0,
                                                    const __bf16* __restrict__ t1,
                                                    __bf16* __restrict__ o) {
  size_t i = ((size_t)blockIdx.x * 256 + threadIdx.x) * 8;
  bf16x8 a = *(const bf16x8*)(t0 + i);
  bf16x8 b = *(const bf16x8*)(t1 + i);
  bf16x8 r;
#pragma unroll
  for (int j = 0; j < 8; ++j) r[j] = (__bf16)((float)a[j] + (float)b[j]);
  *(bf16x8*)(o + i) = r;
}

// ------- GEMM, 2-phase double-buffered (T3 minimum): C = A @ B^T (+bias) -------
// Per K-tile: issue STAGE(t+1 -> buf^1) FIRST, then ds_read+MFMA tile t from
// buf, then one __syncthreads() (its vmcnt(0) drain waits on loads issued a
// full tile earlier -> overlapped with compute). K-split via blockIdx.z.
template <int BM, int BN, int BK, bool OUT_F32, bool BIAS>
__global__ __launch_bounds__(256) void gemm_bt(const __bf16* __restrict__ Amat,
                                               const __bf16* __restrict__ Bmat,
                                               const float* __restrict__ bias,
                                               void* __restrict__ Cout,
                                               int M, int N, int Kred, int ldk) {
  constexpr int WM = BM / 2, WN = BN / 2;
  constexpr int MI = WM / 16, NI = WN / 16;
  __shared__ alignas(16) __bf16 Al[2][BM * BK];
  __shared__ alignas(16) __bf16 Bl[2][BN * BK];

  const int tid = threadIdx.x;
  const int wid = tid >> 6;
  const int lane = tid & 63;
  const int l15 = lane & 15, lhi = lane >> 4;
  const int wr = wid >> 1, wc = wid & 1;

  // bijective XCD swizzle over the x-y plane (nwg % 8 == 0 for our launches)
  const int gx = gridDim.x;
  const int nwg = gx * gridDim.y;
  const int bid = blockIdx.y * gx + blockIdx.x;
  const int swz = (bid & 7) * (nwg >> 3) + (bid >> 3);
  const int m0 = (swz % gx) * BM;
  const int n0 = (swz / gx) * BN;
  const int kbase = blockIdx.z * Kred;
  const int nt = Kred / BK;

  f32x4 acc[MI][NI] = {};

  auto stage = [&](int k0, int b) {
    constexpr int IA = BM * BK / (256 * 8);
#pragma unroll
    for (int it = 0; it < IA; ++it) {
      int o = (it * 256 + tid) * 8;
      int row = o / BK;
      int blk = (o % BK) / 8;
      int col = (blk ^ (row & 7)) * 8;
      gload_lds16(Amat + (size_t)(m0 + row) * ldk + k0 + col,
                  &Al[b][(it * 256 + wid * 64) * 8]);
    }
    constexpr int IB = BN * BK / (256 * 8);
#pragma unroll
    for (int it = 0; it < IB; ++it) {
      int o = (it * 256 + tid) * 8;
      int row = o / BK;
      int blk = (o % BK) / 8;
      int col = (blk ^ (row & 7)) * 8;
      gload_lds16(Bmat + (size_t)(n0 + row) * ldk + k0 + col,
                  &Bl[b][(it * 256 + wid * 64) * 8]);
    }
  };

  stage(kbase, 0);
  __syncthreads();

  for (int t = 0; t < nt; ++t) {
    if (t + 1 < nt) stage(kbase + (t + 1) * BK, (t + 1) & 1);

    const char* Ab_ = (const char*)Al[t & 1];
    const char* Bb_ = (const char*)Bl[t & 1];
#pragma unroll
    for (int kk = 0; kk < BK / 32; ++kk) {
      bf16x8 af[MI], bfv[NI];
#pragma unroll
      for (int mi = 0; mi < MI; ++mi) {
        int row = wr * WM + mi * 16 + l15;
        int blk = (kk * 4 + lhi) ^ (row & 7);
        af[mi] = *(const bf16x8*)(Ab_ + row * (BK * 2) + blk * 16);
      }
#pragma unroll
      for (int ni = 0; ni < NI; ++ni) {
        int row = wc * WN + ni * 16 + l15;
        int blk = (kk * 4 + lhi) ^ (row & 7);
        bfv[ni] = *(const bf16x8*)(Bb_ + row * (BK * 2) + blk * 16);
      }
#pragma unroll
      for (int mi = 0; mi < MI; ++mi)
#pragma unroll
        for (int ni = 0; ni < NI; ++ni)
          acc[mi][ni] = __builtin_amdgcn_mfma_f32_16x16x32_bf16(af[mi], bfv[ni],
                                                                acc[mi][ni], 0, 0, 0);
    }
    __syncthreads();  // drains vmcnt: waits stage(t+1) issued BEFORE compute(t)
  }

  // ---- epilogue: C/D layout col=lane&15, row=(lane>>4)*4+reg ----
  char* cbase = (char*)Cout + (size_t)blockIdx.z * M * N * (OUT_F32 ? 4 : 2);
#pragma unroll
  for (int ni = 0; ni < NI; ++ni) {
    int col = n0 + wc * WN + ni * 16 + l15;
    float bv = 0.f;
    if constexpr (BIAS) bv = bias[col];
#pragma unroll
    for (int mi = 0; mi < MI; ++mi) {
#pragma unroll
      for (int r = 0; r < 4; ++r) {
        int row = m0 + wr * WM + mi * 16 + lhi * 4 + r;
        if constexpr (OUT_F32)
          ((float*)cbase)[(size_t)row * N + col] = acc[mi][ni][r] + bv;
        else
          ((__bf16*)cbase)[(size_t)row * N + col] = (__bf16)acc[mi][ni][r];
      }
    }
  }
}

extern "C" void kernel_launch(void* const* d_in, const int* in_sizes, int n_in,
                              void* d_out, int out_size, void* d_ws, size_t ws_size,
                              hipStream_t stream) {
  const float* x    = (const float*)d_in[0];
  const float* A    = (const float*)d_in[1];
  const float* B    = (const float*)d_in[2];
  const float* bias = (const float*)d_in[3];
  float* out = (float*)d_out;

  // d_out (128+ MiB) doubles as scratch before GEMM2 overwrites it:
  //   [0, 64 MiB)  : xb  = bf16(x)            (consumed by GEMM1)
  //   [64, 80 MiB) : tp  = split-K partials   (consumed by reduce2)
  __bf16* xb = (__bf16*)d_out;
  __bf16* tp = (__bf16*)((char*)d_out + ((size_t)64 << 20));
  char* ws = (char*)d_ws;
  __bf16* Ab = (__bf16*)ws;                        // [D_OUT][RANK] bf16
  __bf16* Bt = (__bf16*)(ws + ((size_t)4 << 20));  // [RANK][D_IN]  bf16
  __bf16* Tt = (__bf16*)(ws + ((size_t)8 << 20));  // [MROWS][RANK] bf16

  hipLaunchKernelGGL(cvt_f32_bf16, dim3(2048), dim3(256), 0, stream,
                     x, xb, (size_t)MROWS * D_IN);
  hipLaunchKernelGGL(cvt_f32_bf16, dim3(512), dim3(256), 0, stream,
                     A, Ab, (size_t)D_OUT * RANK);
  hipLaunchKernelGGL(transpose_cvt, dim3(D_IN / 64, RANK / 64), dim3(256), 0, stream,
                     B, Bt, D_IN, RANK);
  // t_partial[z] = bf16(x) @ B[:, z*2048:(z+1)*2048]   (split-K=2, 128x128 tiles)
  hipLaunchKernelGGL((gemm_bt<128, 128, 64, false, false>),
                     dim3(MROWS / 128, RANK / 128, 2), dim3(256), 0, stream,
                     xb, Bt, nullptr, tp, MROWS, RANK, D_IN / 2, D_IN);
  // Tt = bf16(tp[0] + tp[1])
  hipLaunchKernelGGL(reduce2_bf16, dim3(MROWS * RANK / (256 * 8)), dim3(256), 0, stream,
                     tp, tp + (size_t)MROWS * RANK, Tt);
  // out = Tt @ A^T + bias
  hipLaunchKernelGGL((gemm_bt<128, 128, 64, true, true>),
                     dim3(MROWS / 128, D_OUT / 128, 1), dim3(256), 0, stream,
                     Tt, Ab, bias, out, MROWS, D_OUT, RANK, RANK);
}

// Round 6
// 149.245 us; speedup vs baseline: 1.6636x; 1.0877x over previous
//
#include <hip/hip_runtime.h>

typedef __attribute__((ext_vector_type(8))) __bf16 bf16x8;
typedef __attribute__((ext_vector_type(4))) __bf16 bf16x4;
typedef __attribute__((ext_vector_type(4))) float f32x4;

#define D_OUT 4096
#define D_IN  4096
#define RANK  512
#define MROWS 8192   // BATCH*SEQ

__device__ __forceinline__ void gload_lds16(const void* gsrc, void* ldst) {
  __builtin_amdgcn_global_load_lds(
      (const __attribute__((address_space(1))) void*)gsrc,
      (__attribute__((address_space(3))) void*)ldst, 16, 0, 0);
}

// ---------------- f32 -> bf16 elementwise convert ----------------
__global__ __launch_bounds__(256) void cvt_f32_bf16(const float* __restrict__ in,
                                                    __bf16* __restrict__ out,
                                                    size_t n) {
  size_t i = ((size_t)blockIdx.x * 256 + threadIdx.x) * 4;
  size_t stride = (size_t)gridDim.x * 256 * 4;
  for (; i < n; i += stride) {
    float4 v = *(const float4*)(in + i);
    bf16x4 o = {(__bf16)v.x, (__bf16)v.y, (__bf16)v.z, (__bf16)v.w};
    *(bf16x4*)(out + i) = o;
  }
}

// ------------- f32 [R][C] -> bf16 [C][R] transpose-convert -------------
__global__ __launch_bounds__(256) void transpose_cvt(const float* __restrict__ in,
                                                     __bf16* __restrict__ out,
                                                     int R, int C) {
  __shared__ __bf16 tile[64][72];
  const int r0 = blockIdx.x * 64, c0 = blockIdx.y * 64;
  const int t = threadIdx.x;
  const int tr = t / 16, tc4 = (t % 16) * 4;
#pragma unroll
  for (int i = 0; i < 4; ++i) {
    int r = i * 16 + tr;
    float4 v = *(const float4*)(in + (size_t)(r0 + r) * C + c0 + tc4);
    tile[r][tc4 + 0] = (__bf16)v.x;
    tile[r][tc4 + 1] = (__bf16)v.y;
    tile[r][tc4 + 2] = (__bf16)v.z;
    tile[r][tc4 + 3] = (__bf16)v.w;
  }
  __syncthreads();
#pragma unroll
  for (int i = 0; i < 4; ++i) {
    int c = i * 16 + tr;
    bf16x4 o = {tile[tc4 + 0][c], tile[tc4 + 1][c], tile[tc4 + 2][c], tile[tc4 + 3][c]};
    *(bf16x4*)(out + (size_t)(c0 + c) * R + r0 + tc4) = o;
  }
}

// ---------------- partial-sum reduce + cvt: o = bf16(t0 + t1) ----------------
__global__ __launch_bounds__(256) void reduce2_bf16(const __bf16* __restrict__ t0,
                                                    const __bf16* __restrict__ t1,
                                                    __bf16* __restrict__ o) {
  size_t i = ((size_t)blockIdx.x * 256 + threadIdx.x) * 8;
  bf16x8 a = *(const bf16x8*)(t0 + i);
  bf16x8 b = *(const bf16x8*)(t1 + i);
  bf16x8 r;
#pragma unroll
  for (int j = 0; j < 8; ++j) r[j] = (__bf16)((float)a[j] + (float)b[j]);
  *(bf16x8*)(o + i) = r;
}

// ------------- GEMM (m97 structure, NO XCD swizzle): C = A @ B^T (+bias) -------------
// K-split via blockIdx.z: each z computes Kred columns starting at z*Kred
// (row stride ldk), writing to its own C slice (Cout + z*M*N).
// global_load_lds width-16 staging, XOR-swizzled LDS, 4 waves as 2x2.
template <int BM, int BN, int BK, bool OUT_F32, bool BIAS>
__global__ __launch_bounds__(256) void gemm_bt(const __bf16* __restrict__ Amat,
                                               const __bf16* __restrict__ Bmat,
                                               const float* __restrict__ bias,
                                               void* __restrict__ Cout,
                                               int M, int N, int Kred, int ldk) {
  constexpr int WM = BM / 2, WN = BN / 2;
  constexpr int MI = WM / 16, NI = WN / 16;
  __shared__ alignas(16) __bf16 Al[BM * BK];
  __shared__ alignas(16) __bf16 Bl[BN * BK];

  const int tid = threadIdx.x;
  const int wid = tid >> 6;
  const int lane = tid & 63;
  const int l15 = lane & 15, lhi = lane >> 4;
  const int wr = wid >> 1, wc = wid & 1;

  // plain tile mapping — default bid round-robin across XCDs makes all 8 XCDs
  // stream the same A-rows concurrently (constructive L2/L3 sharing; inputs
  // are L3-resident here, the regime where XCD swizzle hurts)
  const int m0 = blockIdx.x * BM;
  const int n0 = blockIdx.y * BN;
  const int kbase = blockIdx.z * Kred;

  f32x4 acc[MI][NI] = {};

  for (int k0 = kbase; k0 < kbase + Kred; k0 += BK) {
    constexpr int IA = BM * BK / (256 * 8);
#pragma unroll
    for (int it = 0; it < IA; ++it) {
      int o = (it * 256 + tid) * 8;
      int row = o / BK;
      int blk = (o % BK) / 8;
      int col = (blk ^ (row & 7)) * 8;
      gload_lds16(Amat + (size_t)(m0 + row) * ldk + k0 + col,
                  Al + (it * 256 + wid * 64) * 8);
    }
    constexpr int IB = BN * BK / (256 * 8);
#pragma unroll
    for (int it = 0; it < IB; ++it) {
      int o = (it * 256 + tid) * 8;
      int row = o / BK;
      int blk = (o % BK) / 8;
      int col = (blk ^ (row & 7)) * 8;
      gload_lds16(Bmat + (size_t)(n0 + row) * ldk + k0 + col,
                  Bl + (it * 256 + wid * 64) * 8);
    }
    __syncthreads();

#pragma unroll
    for (int kk = 0; kk < BK / 32; ++kk) {
      bf16x8 af[MI], bfv[NI];
#pragma unroll
      for (int mi = 0; mi < MI; ++mi) {
        int row = wr * WM + mi * 16 + l15;
        int blk = (kk * 4 + lhi) ^ (row & 7);
        af[mi] = *(const bf16x8*)((const char*)Al + row * (BK * 2) + blk * 16);
      }
#pragma unroll
      for (int ni = 0; ni < NI; ++ni) {
        int row = wc * WN + ni * 16 + l15;
        int blk = (kk * 4 + lhi) ^ (row & 7);
        bfv[ni] = *(const bf16x8*)((const char*)Bl + row * (BK * 2) + blk * 16);
      }
#pragma unroll
      for (int mi = 0; mi < MI; ++mi)
#pragma unroll
        for (int ni = 0; ni < NI; ++ni)
          acc[mi][ni] = __builtin_amdgcn_mfma_f32_16x16x32_bf16(af[mi], bfv[ni],
                                                                acc[mi][ni], 0, 0, 0);
    }
    __syncthreads();
  }

  // ---- epilogue: C/D layout col=lane&15, row=(lane>>4)*4+reg ----
  char* cbase = (char*)Cout + (size_t)blockIdx.z * M * N * (OUT_F32 ? 4 : 2);
#pragma unroll
  for (int ni = 0; ni < NI; ++ni) {
    int col = n0 + wc * WN + ni * 16 + l15;
    float bv = 0.f;
    if constexpr (BIAS) bv = bias[col];
#pragma unroll
    for (int mi = 0; mi < MI; ++mi) {
#pragma unroll
      for (int r = 0; r < 4; ++r) {
        int row = m0 + wr * WM + mi * 16 + lhi * 4 + r;
        if constexpr (OUT_F32)
          ((float*)cbase)[(size_t)row * N + col] = acc[mi][ni][r] + bv;
        else
          ((__bf16*)cbase)[(size_t)row * N + col] = (__bf16)acc[mi][ni][r];
      }
    }
  }
}

extern "C" void kernel_launch(void* const* d_in, const int* in_sizes, int n_in,
                              void* d_out, int out_size, void* d_ws, size_t ws_size,
                              hipStream_t stream) {
  const float* x    = (const float*)d_in[0];
  const float* A    = (const float*)d_in[1];
  const float* B    = (const float*)d_in[2];
  const float* bias = (const float*)d_in[3];
  float* out = (float*)d_out;

  // d_out (128+ MiB) doubles as scratch before GEMM2 overwrites it:
  //   [0, 64 MiB)  : xb  = bf16(x)            (consumed by GEMM1)
  //   [64, 80 MiB) : tp  = split-K partials   (consumed by reduce2)
  __bf16* xb = (__bf16*)d_out;
  __bf16* tp = (__bf16*)((char*)d_out + ((size_t)64 << 20));
  char* ws = (char*)d_ws;
  __bf16* Ab = (__bf16*)ws;                        // [D_OUT][RANK] bf16
  __bf16* Bt = (__bf16*)(ws + ((size_t)4 << 20));  // [RANK][D_IN]  bf16
  __bf16* Tt = (__bf16*)(ws + ((size_t)8 << 20));  // [MROWS][RANK] bf16

  hipLaunchKernelGGL(cvt_f32_bf16, dim3(2048), dim3(256), 0, stream,
                     x, xb, (size_t)MROWS * D_IN);
  hipLaunchKernelGGL(cvt_f32_bf16, dim3(512), dim3(256), 0, stream,
                     A, Ab, (size_t)D_OUT * RANK);
  hipLaunchKernelGGL(transpose_cvt, dim3(D_IN / 64, RANK / 64), dim3(256), 0, stream,
                     B, Bt, D_IN, RANK);
  // t_partial[z] = bf16(x) @ B[:, z*2048:(z+1)*2048]   (split-K=2, 128x128 tiles)
  hipLaunchKernelGGL((gemm_bt<128, 128, 64, false, false>),
                     dim3(MROWS / 128, RANK / 128, 2), dim3(256), 0, stream,
                     xb, Bt, nullptr, tp, MROWS, RANK, D_IN / 2, D_IN);
  // Tt = bf16(tp[0] + tp[1])
  hipLaunchKernelGGL(reduce2_bf16, dim3(MROWS * RANK / (256 * 8)), dim3(256), 0, stream,
                     tp, tp + (size_t)MROWS * RANK, Tt);
  // out = Tt @ A^T + bias
  hipLaunchKernelGGL((gemm_bt<128, 128, 64, true, true>),
                     dim3(MROWS / 128, D_OUT / 128, 1), dim3(256), 0, stream,
                     Tt, Ab, bias, out, MROWS, D_OUT, RANK, RANK);
}

// Round 7
// 141.175 us; speedup vs baseline: 1.7587x; 1.0572x over previous
//
#include <hip/hip_runtime.h>

typedef __attribute__((ext_vector_type(8))) __bf16 bf16x8;
typedef __attribute__((ext_vector_type(4))) __bf16 bf16x4;
typedef __attribute__((ext_vector_type(4))) float f32x4;

#define D_OUT 4096
#define D_IN  4096
#define RANK  512
#define MROWS 8192   // BATCH*SEQ

__device__ __forceinline__ void gload_lds16(const void* gsrc, void* ldst) {
  __builtin_amdgcn_global_load_lds(
      (const __attribute__((address_space(1))) void*)gsrc,
      (__attribute__((address_space(3))) void*)ldst, 16, 0, 0);
}

// ---------------- f32 -> bf16 elementwise convert (A) ----------------
__global__ __launch_bounds__(256) void cvt_f32_bf16(const float* __restrict__ in,
                                                    __bf16* __restrict__ out,
                                                    size_t n) {
  size_t i = ((size_t)blockIdx.x * 256 + threadIdx.x) * 4;
  size_t stride = (size_t)gridDim.x * 256 * 4;
  for (; i < n; i += stride) {
    float4 v = *(const float4*)(in + i);
    bf16x4 o = {(__bf16)v.x, (__bf16)v.y, (__bf16)v.z, (__bf16)v.w};
    *(bf16x4*)(out + i) = o;
  }
}

// ------------- f32 [R][C] -> bf16 [C][R] transpose-convert (B) -------------
__global__ __launch_bounds__(256) void transpose_cvt(const float* __restrict__ in,
                                                     __bf16* __restrict__ out,
                                                     int R, int C) {
  __shared__ __bf16 tile[64][72];
  const int r0 = blockIdx.x * 64, c0 = blockIdx.y * 64;
  const int t = threadIdx.x;
  const int tr = t / 16, tc4 = (t % 16) * 4;
#pragma unroll
  for (int i = 0; i < 4; ++i) {
    int r = i * 16 + tr;
    float4 v = *(const float4*)(in + (size_t)(r0 + r) * C + c0 + tc4);
    tile[r][tc4 + 0] = (__bf16)v.x;
    tile[r][tc4 + 1] = (__bf16)v.y;
    tile[r][tc4 + 2] = (__bf16)v.z;
    tile[r][tc4 + 3] = (__bf16)v.w;
  }
  __syncthreads();
#pragma unroll
  for (int i = 0; i < 4; ++i) {
    int c = i * 16 + tr;
    bf16x4 o = {tile[tc4 + 0][c], tile[tc4 + 1][c], tile[tc4 + 2][c], tile[tc4 + 3][c]};
    *(bf16x4*)(out + (size_t)(c0 + c) * R + r0 + tc4) = o;
  }
}

// ---------------- partial-sum reduce + cvt: o = bf16(t0 + t1) ----------------
__global__ __launch_bounds__(256) void reduce2_bf16(const __bf16* __restrict__ t0,
                                                    const __bf16* __restrict__ t1,
                                                    __bf16* __restrict__ o) {
  size_t i = ((size_t)blockIdx.x * 256 + threadIdx.x) * 8;
  bf16x8 a = *(const bf16x8*)(t0 + i);
  bf16x8 b = *(const bf16x8*)(t1 + i);
  bf16x8 r;
#pragma unroll
  for (int j = 0; j < 8; ++j) r[j] = (__bf16)((float)a[j] + (float)b[j]);
  *(bf16x8*)(o + i) = r;
}

// ---- GEMM1 fused-cast: C[M,N] = bf16(Xf32[M,:]) @ Bmat[N,:]^T, bf16 out ----
// X staged as RAW F32 into LDS via global_load_lds (async path preserved);
// f32->bf16 convert happens on the LDS->VGPR fragment read (2x ds_read_b128
// + v_cvt_pk). Removes the separate cvt_x pass (201 MB HBM traffic).
// K-split via blockIdx.z. No XCD swizzle (L3-resident regime).
template <int BM, int BN, int BK>
__global__ __launch_bounds__(256) void gemm1_xf32(const float* __restrict__ Xf,
                                                  const __bf16* __restrict__ Bmat,
                                                  __bf16* __restrict__ Cout,
                                                  int M, int N, int Kred, int ldk) {
  constexpr int WM = BM / 2, WN = BN / 2;
  constexpr int MI = WM / 16, NI = WN / 16;
  __shared__ alignas(16) float Af[BM * BK];    // 32 KB f32 x-tile
  __shared__ alignas(16) __bf16 Bl[BN * BK];   // 16 KB bf16 B-tile

  const int tid = threadIdx.x;
  const int wid = tid >> 6;
  const int lane = tid & 63;
  const int l15 = lane & 15, lhi = lane >> 4;
  const int wr = wid >> 1, wc = wid & 1;

  const int m0 = blockIdx.x * BM;
  const int n0 = blockIdx.y * BN;
  const int kbase = blockIdx.z * Kred;

  f32x4 acc[MI][NI] = {};

  for (int k0 = kbase; k0 < kbase + Kred; k0 += BK) {
    // ---- A tile (f32): 16B = 4 f32 per thread per issue ----
    constexpr int IAF = BM * BK / (256 * 4);
#pragma unroll
    for (int it = 0; it < IAF; ++it) {
      int o = (it * 256 + tid) * 4;          // f32 element offset
      int row = o / BK;
      int b = (o % BK) / 4;                  // 16B block in row (0..15)
      int colsw = (b ^ (row & 7)) * 4;       // inverse swizzle (involution)
      gload_lds16(Xf + (size_t)(m0 + row) * ldk + k0 + colsw,
                  Af + (it * 256 + wid * 64) * 4);
    }
    // ---- B tile (bf16): as before ----
    constexpr int IB = BN * BK / (256 * 8);
#pragma unroll
    for (int it = 0; it < IB; ++it) {
      int o = (it * 256 + tid) * 8;
      int row = o / BK;
      int blk = (o % BK) / 8;
      int col = (blk ^ (row & 7)) * 8;
      gload_lds16(Bmat + (size_t)(n0 + row) * ldk + k0 + col,
                  Bl + (it * 256 + wid * 64) * 8);
    }
    __syncthreads();

#pragma unroll
    for (int kk = 0; kk < BK / 32; ++kk) {
      bf16x8 af[MI], bfv[NI];
#pragma unroll
      for (int mi = 0; mi < MI; ++mi) {
        int row = wr * WM + mi * 16 + l15;
        int b0 = (kk * 8 + lhi * 2) ^ (row & 7);   // f32 row = 16 blocks
        const char* base = (const char*)Af + row * (BK * 4);
        f32x4 a0 = *(const f32x4*)(base + b0 * 16);
        f32x4 a1 = *(const f32x4*)(base + (b0 ^ 1) * 16);
#pragma unroll
        for (int j = 0; j < 4; ++j) {
          af[mi][j]     = (__bf16)a0[j];
          af[mi][4 + j] = (__bf16)a1[j];
        }
      }
#pragma unroll
      for (int ni = 0; ni < NI; ++ni) {
        int row = wc * WN + ni * 16 + l15;
        int blk = (kk * 4 + lhi) ^ (row & 7);
        bfv[ni] = *(const bf16x8*)((const char*)Bl + row * (BK * 2) + blk * 16);
      }
#pragma unroll
      for (int mi = 0; mi < MI; ++mi)
#pragma unroll
        for (int ni = 0; ni < NI; ++ni)
          acc[mi][ni] = __builtin_amdgcn_mfma_f32_16x16x32_bf16(af[mi], bfv[ni],
                                                                acc[mi][ni], 0, 0, 0);
    }
    __syncthreads();
  }

  // ---- epilogue: bf16 partial to this z's slice ----
  __bf16* cbase = Cout + (size_t)blockIdx.z * M * N;
#pragma unroll
  for (int ni = 0; ni < NI; ++ni) {
    int col = n0 + wc * WN + ni * 16 + l15;
#pragma unroll
    for (int mi = 0; mi < MI; ++mi) {
#pragma unroll
      for (int r = 0; r < 4; ++r) {
        int row = m0 + wr * WM + mi * 16 + lhi * 4 + r;
        cbase[(size_t)row * N + col] = (__bf16)acc[mi][ni][r];
      }
    }
  }
}

// ------------- GEMM2 (m97 structure, no swizzle): C = A @ B^T + bias, f32 -------------
template <int BM, int BN, int BK>
__global__ __launch_bounds__(256) void gemm_bt_bias(const __bf16* __restrict__ Amat,
                                                    const __bf16* __restrict__ Bmat,
                                                    const float* __restrict__ bias,
                                                    float* __restrict__ Cout,
                                                    int M, int N, int K) {
  constexpr int WM = BM / 2, WN = BN / 2;
  constexpr int MI = WM / 16, NI = WN / 16;
  __shared__ alignas(16) __bf16 Al[BM * BK];
  __shared__ alignas(16) __bf16 Bl[BN * BK];

  const int tid = threadIdx.x;
  const int wid = tid >> 6;
  const int lane = tid & 63;
  const int l15 = lane & 15, lhi = lane >> 4;
  const int wr = wid >> 1, wc = wid & 1;

  const int m0 = blockIdx.x * BM;
  const int n0 = blockIdx.y * BN;

  f32x4 acc[MI][NI] = {};

  for (int k0 = 0; k0 < K; k0 += BK) {
    constexpr int IA = BM * BK / (256 * 8);
#pragma unroll
    for (int it = 0; it < IA; ++it) {
      int o = (it * 256 + tid) * 8;
      int row = o / BK;
      int blk = (o % BK) / 8;
      int col = (blk ^ (row & 7)) * 8;
      gload_lds16(Amat + (size_t)(m0 + row) * K + k0 + col,
                  Al + (it * 256 + wid * 64) * 8);
    }
    constexpr int IB = BN * BK / (256 * 8);
#pragma unroll
    for (int it = 0; it < IB; ++it) {
      int o = (it * 256 + tid) * 8;
      int row = o / BK;
      int blk = (o % BK) / 8;
      int col = (blk ^ (row & 7)) * 8;
      gload_lds16(Bmat + (size_t)(n0 + row) * K + k0 + col,
                  Bl + (it * 256 + wid * 64) * 8);
    }
    __syncthreads();

#pragma unroll
    for (int kk = 0; kk < BK / 32; ++kk) {
      bf16x8 af[MI], bfv[NI];
#pragma unroll
      for (int mi = 0; mi < MI; ++mi) {
        int row = wr * WM + mi * 16 + l15;
        int blk = (kk * 4 + lhi) ^ (row & 7);
        af[mi] = *(const bf16x8*)((const char*)Al + row * (BK * 2) + blk * 16);
      }
#pragma unroll
      for (int ni = 0; ni < NI; ++ni) {
        int row = wc * WN + ni * 16 + l15;
        int blk = (kk * 4 + lhi) ^ (row & 7);
        bfv[ni] = *(const bf16x8*)((const char*)Bl + row * (BK * 2) + blk * 16);
      }
#pragma unroll
      for (int mi = 0; mi < MI; ++mi)
#pragma unroll
        for (int ni = 0; ni < NI; ++ni)
          acc[mi][ni] = __builtin_amdgcn_mfma_f32_16x16x32_bf16(af[mi], bfv[ni],
                                                                acc[mi][ni], 0, 0, 0);
    }
    __syncthreads();
  }

#pragma unroll
  for (int ni = 0; ni < NI; ++ni) {
    int col = n0 + wc * WN + ni * 16 + l15;
    float bv = bias[col];
#pragma unroll
    for (int mi = 0; mi < MI; ++mi) {
#pragma unroll
      for (int r = 0; r < 4; ++r) {
        int row = m0 + wr * WM + mi * 16 + lhi * 4 + r;
        Cout[(size_t)row * N + col] = acc[mi][ni][r] + bv;
      }
    }
  }
}

extern "C" void kernel_launch(void* const* d_in, const int* in_sizes, int n_in,
                              void* d_out, int out_size, void* d_ws, size_t ws_size,
                              hipStream_t stream) {
  const float* x    = (const float*)d_in[0];
  const float* A    = (const float*)d_in[1];
  const float* B    = (const float*)d_in[2];
  const float* bias = (const float*)d_in[3];
  float* out = (float*)d_out;

  // d_out (128+ MiB) doubles as scratch before GEMM2 overwrites it:
  //   [64, 80 MiB) : tp = split-K partials (consumed by reduce2)
  __bf16* tp = (__bf16*)((char*)d_out + ((size_t)64 << 20));
  char* ws = (char*)d_ws;
  __bf16* Ab = (__bf16*)ws;                        // [D_OUT][RANK] bf16
  __bf16* Bt = (__bf16*)(ws + ((size_t)4 << 20));  // [RANK][D_IN]  bf16
  __bf16* Tt = (__bf16*)(ws + ((size_t)8 << 20));  // [MROWS][RANK] bf16

  hipLaunchKernelGGL(cvt_f32_bf16, dim3(512), dim3(256), 0, stream,
                     A, Ab, (size_t)D_OUT * RANK);
  hipLaunchKernelGGL(transpose_cvt, dim3(D_IN / 64, RANK / 64), dim3(256), 0, stream,
                     B, Bt, D_IN, RANK);
  // t_partial[z] = bf16(x) @ B[:, z*2048:(z+1)*2048]  (fused cast, split-K=2)
  hipLaunchKernelGGL((gemm1_xf32<128, 128, 64>),
                     dim3(MROWS / 128, RANK / 128, 2), dim3(256), 0, stream,
                     x, Bt, tp, MROWS, RANK, D_IN / 2, D_IN);
  // Tt = bf16(tp[0] + tp[1])
  hipLaunchKernelGGL(reduce2_bf16, dim3(MROWS * RANK / (256 * 8)), dim3(256), 0, stream,
                     tp, tp + (size_t)MROWS * RANK, Tt);
  // out = Tt @ A^T + bias
  hipLaunchKernelGGL((gemm_bt_bias<128, 128, 64>),
                     dim3(MROWS / 128, D_OUT / 128), dim3(256), 0, stream,
                     Tt, Ab, bias, out, MROWS, D_OUT, RANK);
}